// Round 13
// baseline (888.209 us; speedup 1.0000x reference)
//
#include <hip/hip_runtime.h>

// MultiAgentDRQN R13. Root cause across R9-R12: 192 weight floats/lane never
// fits the de-facto 128-VGPR cap -> per-step reloads; and wave-level tricks
// (bounds hints, 2-seq amortization) all failed. Fix by construction: 64
// weights/lane everywhere (fc1 split-K proved this size: VGPR~90, no spill).
//   gru5_k: 3 waves = 1 sequence (gate-split r/z/n). 2048 blocks x 192thr ->
//           6 waves/SIMD. Per step: 64-FMA matvec/wave; r,z write sigmoids to
//           LDS; barrier; n-wave: ng=tanh(gi_n+rg*ghn), h'=(1-z)n+z h, write
//           hs dbuf + h->global; barrier. fc2/argmax HOISTED out.
//   fc2q_k: parallel fc2+max/argmax from h (h stored into a_buf -- a is dead
//           after gi5_k; no extra workspace).
//   gi5_k : gate-split gi (6144 waves, 64 wt/lane, no barriers, no reloads).
//   fc1_k : unchanged (R8 split-K).
// All fp32 (argmax-flip safety). Fallback: R1 fused kernel if ws too small.

namespace {
constexpr int kB = 256, kT = 200, kN = 8, kObs = 128, kH = 64, kOut = 16;
constexpr int kRows = kB * kT * kN;                  // 409600
constexpr size_t kABytes  = (size_t)kRows * 64 * 4;  // 100 MB (a, then h)
constexpr size_t kGiBytes = (size_t)kRows * 192 * 4; // 300 MB
}

// ------- fc1_k: a[r][64] = relu(x_r . W1^T + b1), split-K 2 waves/row --------
__global__ __launch_bounds__(256, 2)
void fc1_k(const float* __restrict__ obs, const int* __restrict__ agent,
           const float* __restrict__ W1, const float* __restrict__ b1,
           float* __restrict__ a_out) {
  __shared__ float xs[2][2][128];   // [engine][buf][k]
  __shared__ float ps[2][2][64];    // [engine][buf][out] partial sums
  __shared__ float ohs[512];        // ohs[n*64+l] = W1[l][128+agent[n]]
  const int tid = threadIdx.x, lane = tid & 63, w = tid >> 6;
  const int e = w >> 1, p = w & 1;  // engine, k-half

  for (int i = tid; i < 512; i += 256) {
    int n = i >> 6, l = i & 63;
    ohs[i] = W1[(size_t)l * 136 + 128 + agent[n]];
  }

  float4 wv[16];
  #pragma unroll
  for (int k = 0; k < 16; ++k)
    wv[k] = *(const float4*)(W1 + (size_t)lane * 136 + p * 64 + k * 4);
  const float b1r = b1[lane];       // used by finishing wave (p==1)

  constexpr int ROWS = 100;         // 4096 engines x 100 rows = 409600
  const int eng = blockIdx.x * 2 + e;
  const int r0 = eng * ROWS;
  const int et = p * 64 + lane;     // engine-local staging index [0,128)

  xs[e][0][et] = obs[(size_t)r0 * 128 + et];
  float xq = obs[(size_t)(r0 + 1) * 128 + et];
  __syncthreads();                  // covers ohs + row-0 staging

  #pragma unroll 1
  for (int i = 0; i < ROWS; ++i) {
    const int r = r0 + i;
    if (i + 1 < ROWS) xs[e][(i + 1) & 1][et] = xq;
    const int nr = (i + 2 < ROWS) ? (r0 + i + 2) : (r0 + ROWS - 1);
    xq = obs[(size_t)nr * 128 + et];

    const float* xb = xs[e][i & 1] + p * 64;
    float a0 = 0.f, a1 = 0.f, a2 = 0.f, a3 = 0.f;
    #pragma unroll
    for (int k = 0; k < 16; ++k) {
      float4 xp = *(const float4*)(xb + k * 4);   // same-addr broadcast read
      a0 = fmaf(wv[k].x, xp.x, a0);
      a1 = fmaf(wv[k].y, xp.y, a1);
      a2 = fmaf(wv[k].z, xp.z, a2);
      a3 = fmaf(wv[k].w, xp.w, a3);
    }
    const float part = (a0 + a1) + (a2 + a3);
    if (p == 0) ps[e][i & 1][lane] = part;
    __syncthreads();                // ps(i) visible; dbuf protects i+2 reuse
    if (p == 1) {
      float av = part + ps[e][i & 1][lane] + b1r + ohs[(r & 7) * 64 + lane];
      a_out[(size_t)r * 64 + lane] = fmaxf(av, 0.f);
    }
  }
}

// ---- gi5_k: gate-split gi. wave = (engine, gate); 64 weights/lane ----------
__global__ __launch_bounds__(256, 2)
void gi5_k(const float* __restrict__ a_glob, const float* __restrict__ Wih,
           const float* __restrict__ bih, float* __restrict__ gi_out) {
  __shared__ float as_[4][2][64];
  const int tid = threadIdx.x, lane = tid & 63, w = tid >> 6;
  const int W = blockIdx.x * 4 + w;       // 6144 gate-waves
  const int eng = W / 3, g = W - eng * 3; // 2048 engines x 3 gates

  float wg[64];
  #pragma unroll
  for (int k = 0; k < 64; k += 4)
    *(float4*)&wg[k] = *(const float4*)(Wih + (size_t)(g * 64 + lane) * 64 + k);
  const float bg = bih[g * 64 + lane];

  const int r0 = eng * 200;
  float (*ab)[64] = as_[w];
  ab[0][lane] = a_glob[(size_t)r0 * 64 + lane];
  float aq = a_glob[(size_t)(r0 + 1) * 64 + lane];

  #pragma unroll 1
  for (int i = 0; i < 200; ++i) {
    const int r = r0 + i;
    if (i + 1 < 200) ab[(i + 1) & 1][lane] = aq;
    const int nr = (i + 2 < 200) ? (r0 + i + 2) : (r0 + 199);
    aq = a_glob[(size_t)nr * 64 + lane];

    const float* ap = ab[i & 1];
    float a0 = 0.f, a1 = 0.f;
    #pragma unroll
    for (int k = 0; k < 64; k += 4) {
      float4 av = *(const float4*)(ap + k);   // same-addr broadcast read
      a0 = fmaf(wg[k],     av.x, a0);
      a1 = fmaf(wg[k + 1], av.y, a1);
      a0 = fmaf(wg[k + 2], av.z, a0);
      a1 = fmaf(wg[k + 3], av.w, a1);
    }
    gi_out[(size_t)r * 192 + g * 64 + lane] = bg + a0 + a1;
  }
}

// ---- gru5_k: 3 waves = 1 sequence (gate-split), 2 barriers/step -------------
__global__ __launch_bounds__(192, 2)
void gru5_k(const float* __restrict__ gi_glob,
            const float* __restrict__ Whh, const float* __restrict__ bhh,
            float* __restrict__ h_out) {
  __shared__ float hsb[2][64];
  __shared__ float rgs[64];
  __shared__ float zgs[64];
  const int tid = threadIdx.x, lane = tid & 63, g = tid >> 6; // 0=r,1=z,2=n

  float wg[64];  // Whh row g*64+lane (64 regs -- comfortably under cap)
  #pragma unroll
  for (int k = 0; k < 64; k += 4)
    *(float4*)&wg[k] = *(const float4*)(Whh + (size_t)(g * 64 + lane) * 64 + k);
  const float bg = bhh[g * 64 + lane];

  const int s = blockIdx.x;               // sequence = b*8 + n
  const size_t rbase = (size_t)(s >> 3) * 1600 + (s & 7);
  const float* gip = gi_glob + rbase * 192 + g * 64 + lane; // +t*1536

  if (g == 0) hsb[0][lane] = 0.f;
  float h = 0.f;                          // tracked by n-wave
  float giA = gip[0];
  float giB = gip[1536];
  __syncthreads();

#define GRU5_STEP(T, G, TN)                                                    \
  {                                                                            \
    const int t_ = (T);                                                        \
    const int cur_ = t_ & 1;                                                   \
    const float* hb_ = hsb[cur_];                                              \
    float a0 = 0.f, a1 = 0.f;                                                  \
    _Pragma("unroll") for (int k = 0; k < 64; k += 4) {                        \
      float4 hp = *(const float4*)(hb_ + k);                                   \
      a0 = fmaf(wg[k],     hp.x, a0);                                          \
      a1 = fmaf(wg[k + 1], hp.y, a1);                                          \
      a0 = fmaf(wg[k + 2], hp.z, a0);                                          \
      a1 = fmaf(wg[k + 3], hp.w, a1);                                          \
    }                                                                          \
    const float acc_ = bg + a0 + a1;      /* gh_g (bhh folded) */              \
    const float gi_ = (G);                                                     \
    const int tn_ = (TN) > 199 ? 199 : (TN);                                   \
    (G) = gip[(size_t)tn_ * 1536];                                             \
    if (g == 0)      rgs[lane] = 1.f / (1.f + __expf(-(gi_ + acc_)));          \
    else if (g == 1) zgs[lane] = 1.f / (1.f + __expf(-(gi_ + acc_)));          \
    __syncthreads();                      /* A: rg/zg visible */               \
    if (g == 2) {                                                              \
      const float rg_ = rgs[lane], zg_ = zgs[lane];                            \
      const float e2_ = __expf(2.f * (gi_ + rg_ * acc_));                      \
      const float ng_ = 1.f - 2.f / (e2_ + 1.f);   /* tanh */                  \
      h = (1.f - zg_) * ng_ + zg_ * h;                                         \
      hsb[cur_ ^ 1][lane] = h;                                                 \
      h_out[(rbase + (size_t)t_ * 8) * 64 + lane] = h;                         \
    }                                                                          \
    __syncthreads();                      /* B: h' visible */                  \
  }

  #pragma unroll 1
  for (int t = 0; t < 200; t += 2) {
    GRU5_STEP(t,     giA, t + 2)
    GRU5_STEP(t + 1, giB, t + 3)
  }
#undef GRU5_STEP
}

// ---- fc2q_k: q = W2 h + b2, max, argmax (parallel over all rows) ------------
__global__ __launch_bounds__(256, 2)
void fc2q_k(const float* __restrict__ h_all,
            const float* __restrict__ W2, const float* __restrict__ b2,
            float* __restrict__ out) {
  __shared__ float hs[4][2][64];
  const int tid = threadIdx.x, lane = tid & 63, w = tid >> 6;
  const int m = lane & 15, qt = lane >> 4;
  float w2r[16];
  #pragma unroll
  for (int j = 0; j < 16; j += 4)
    *(float4*)&w2r[j] = *(const float4*)(W2 + (size_t)m * 64 + qt * 16 + j);
  const float b2r = b2[m];

  constexpr int ROWS = 100;               // 4096 waves x 100 rows
  const int gwave = blockIdx.x * 4 + w;
  const int r0 = gwave * ROWS;
  float (*hw)[64] = hs[w];

  float* outq  = out;
  float* outmv = out + (size_t)kRows * 16;
  float* outma = outmv + kRows;

  hw[0][lane] = h_all[(size_t)r0 * 64 + lane];
  float hq = h_all[(size_t)(r0 + 1) * 64 + lane];

  #pragma unroll 1
  for (int i = 0; i < ROWS; ++i) {
    const int r = r0 + i;
    if (i + 1 < ROWS) hw[(i + 1) & 1][lane] = hq;
    const int nr = (i + 2 < ROWS) ? (r0 + i + 2) : (r0 + ROWS - 1);
    hq = h_all[(size_t)nr * 64 + lane];

    const float* hb = hw[i & 1] + qt * 16;
    float q0 = 0.f, q1 = 0.f;
    #pragma unroll
    for (int j = 0; j < 16; j += 4) {
      float4 hp = *(const float4*)(hb + j);
      q0 = fmaf(w2r[j],     hp.x, q0);
      q1 = fmaf(w2r[j + 1], hp.y, q1);
      q0 = fmaf(w2r[j + 2], hp.z, q0);
      q1 = fmaf(w2r[j + 3], hp.w, q1);
    }
    float q = q0 + q1;
    q += __shfl_xor(q, 16);
    q += __shfl_xor(q, 32);
    q += b2r;
    if (lane < 16) outq[(size_t)r * 16 + m] = q;

    float bv = q; int bi = m;
    #pragma unroll
    for (int d = 1; d < 16; d <<= 1) {
      float ov = __shfl_xor(bv, d, 16);
      int oi = __shfl_xor(bi, d, 16);
      if (ov > bv || (ov == bv && oi < bi)) { bv = ov; bi = oi; }
    }
    if (lane == 0) { outmv[r] = bv; outma[r] = (float)bi; }
  }
}

// ---------------- R1 fallback (no/small workspace) ---------------------------
namespace fb {
constexpr int kW1Pitch = 137, kHPitch = 65;
constexpr int OFF_W1 = 0;
constexpr int OFF_WIH = OFF_W1 + 64 * kW1Pitch;
constexpr int OFF_WHH = OFF_WIH + 192 * kHPitch;
constexpr int OFF_W2 = OFF_WHH + 192 * kHPitch;
constexpr int OFF_B1 = OFF_W2 + 16 * kHPitch;
constexpr int OFF_BIH = OFF_B1 + 64;
constexpr int OFF_BHH = OFF_BIH + 192;
constexpr int OFF_B2 = OFF_BHH + 192;
constexpr int LDS_FLOATS = OFF_B2 + 16;
}

__device__ __forceinline__ float bcastf(float v, int l) {
  return __int_as_float(__builtin_amdgcn_readlane(__float_as_int(v), l));
}

__global__ __launch_bounds__(512, 1)
void drqn_fused(const float* __restrict__ obs, const int* __restrict__ agent,
                const float* __restrict__ W1, const float* __restrict__ b1,
                const float* __restrict__ Wih, const float* __restrict__ Whh,
                const float* __restrict__ bih, const float* __restrict__ bhh,
                const float* __restrict__ W2, const float* __restrict__ b2,
                float* __restrict__ out) {
  using namespace fb;
  extern __shared__ float lds[];
  float* W1s = lds + OFF_W1; float* Wihs = lds + OFF_WIH;
  float* Whhs = lds + OFF_WHH; float* W2s = lds + OFF_W2;
  float* b1s = lds + OFF_B1; float* bihs = lds + OFF_BIH;
  float* bhhs = lds + OFF_BHH; float* b2s = lds + OFF_B2;
  const int tid = threadIdx.x;
  for (int i = tid; i < 64 * 136; i += 512) { int r = i / 136, c = i - r * 136; W1s[r * kW1Pitch + c] = W1[i]; }
  for (int i = tid; i < 192 * 64; i += 512) { int r = i >> 6, c = i & 63; Wihs[r * kHPitch + c] = Wih[i]; }
  for (int i = tid; i < 192 * 64; i += 512) { int r = i >> 6, c = i & 63; Whhs[r * kHPitch + c] = Whh[i]; }
  for (int i = tid; i < 16 * 64; i += 512) { int r = i >> 6, c = i & 63; W2s[r * kHPitch + c] = W2[i]; }
  if (tid < 64) b1s[tid] = b1[tid];
  if (tid < 192) bihs[tid] = bih[tid];
  if (tid < 192) bhhs[tid] = bhh[tid];
  if (tid < 16) b2s[tid] = b2[tid];
  __syncthreads();
  const int wave = tid >> 6, lane = tid & 63;
  const int s = blockIdx.x * 8 + wave;
  const int b = s >> 3, n = s & 7;
  const int acol = 128 + agent[n];
  const float* obase = obs + (((size_t)b * kT) * kN + n) * kObs;
  const size_t qbase = (((size_t)b * kT) * kN + n) * kOut;
  const size_t mbase = ((size_t)b * kT) * kN + n;
  float* outq = out;
  float* outmv = out + (size_t)kB * kT * kN * kOut;
  float* outma = outmv + (size_t)kB * kT * kN;
  float h = 0.f;
  float xa = obase[lane], xb = obase[64 + lane];
  #pragma unroll 1
  for (int t = 0; t < kT; ++t) {
    float xan = 0.f, xbn = 0.f;
    if (t + 1 < kT) { const float* p = obase + (size_t)(t + 1) * kN * kObs; xan = p[lane]; xbn = p[64 + lane]; }
    float acc = b1s[lane] + W1s[lane * kW1Pitch + acol];
    #pragma unroll
    for (int k = 0; k < 64; ++k) acc += W1s[lane * kW1Pitch + k] * bcastf(xa, k);
    #pragma unroll
    for (int k = 0; k < 64; ++k) acc += W1s[lane * kW1Pitch + 64 + k] * bcastf(xb, k);
    float a = fmaxf(acc, 0.f);
    float air = bihs[lane], aiz = bihs[64 + lane], ain = bihs[128 + lane];
    #pragma unroll
    for (int k = 0; k < 64; ++k) {
      float sa = bcastf(a, k);
      air += Wihs[lane * kHPitch + k] * sa;
      aiz += Wihs[(64 + lane) * kHPitch + k] * sa;
      ain += Wihs[(128 + lane) * kHPitch + k] * sa;
    }
    float ghr = bhhs[lane], ghz = bhhs[64 + lane], ghn = bhhs[128 + lane];
    #pragma unroll
    for (int k = 0; k < 64; ++k) {
      float sh = bcastf(h, k);
      ghr += Whhs[lane * kHPitch + k] * sh;
      ghz += Whhs[(64 + lane) * kHPitch + k] * sh;
      ghn += Whhs[(128 + lane) * kHPitch + k] * sh;
    }
    float rg = 1.f / (1.f + expf(-(air + ghr)));
    float zg = 1.f / (1.f + expf(-(aiz + ghz)));
    float ng = tanhf(ain + rg * ghn);
    h = (1.f - zg) * ng + zg * h;
    const int m = lane & 15;
    float q = b2s[m];
    #pragma unroll
    for (int k = 0; k < 64; ++k) q += W2s[m * kHPitch + k] * bcastf(h, k);
    if (lane < 16) outq[qbase + (size_t)t * kN * kOut + m] = q;
    float bv = q; int bi = m;
    #pragma unroll
    for (int d = 1; d < 16; d <<= 1) {
      float ov = __shfl_xor(bv, d, 16);
      int oi = __shfl_xor(bi, d, 16);
      if (ov > bv || (ov == bv && oi < bi)) { bv = ov; bi = oi; }
    }
    if (lane == 0) { outmv[mbase + (size_t)t * kN] = bv; outma[mbase + (size_t)t * kN] = (float)bi; }
    xa = xan; xb = xbn;
  }
}

extern "C" void kernel_launch(void* const* d_in, const int* in_sizes, int n_in,
                              void* d_out, int out_size, void* d_ws, size_t ws_size,
                              hipStream_t stream) {
  const float* obs  = (const float*)d_in[0];
  const int* agent  = (const int*)d_in[1];
  const float* W1   = (const float*)d_in[2];
  const float* b1   = (const float*)d_in[3];
  const float* Wih  = (const float*)d_in[4];
  const float* Whh  = (const float*)d_in[5];
  const float* bih  = (const float*)d_in[6];
  const float* bhh  = (const float*)d_in[7];
  const float* W2   = (const float*)d_in[8];
  const float* b2   = (const float*)d_in[9];
  float* out = (float*)d_out;

  if (ws_size >= kABytes + kGiBytes) {
    float* a_buf  = (float*)d_ws;          // a, then reused as h
    float* gi_buf = (float*)((char*)d_ws + kABytes);
    fc1_k <<<dim3(2048), dim3(256), 0, stream>>>(obs, agent, W1, b1, a_buf);
    gi5_k <<<dim3(1536), dim3(256), 0, stream>>>(a_buf, Wih, bih, gi_buf);
    gru5_k<<<dim3(2048), dim3(192), 0, stream>>>(gi_buf, Whh, bhh, a_buf);
    fc2q_k<<<dim3(1024), dim3(256), 0, stream>>>(a_buf, W2, b2, out);
  } else {
    (void)hipFuncSetAttribute((const void*)drqn_fused,
                              hipFuncAttributeMaxDynamicSharedMemorySize,
                              fb::LDS_FLOATS * 4);
    drqn_fused<<<dim3(256), dim3(512), fb::LDS_FLOATS * 4, stream>>>(
        obs, agent, W1, b1, Wih, Whh, bih, bhh, W2, b2, out);
  }
}